// Round 6
// baseline (1742.922 us; speedup 1.0000x reference)
//
#include <hip/hip_runtime.h>
#include <hip/hip_fp16.h>
#include <math.h>

// VolumeCarver R6: LDS-segmented table gather + fused in-block scan.
// Global divergent gathers are capped at ~0.5 addr/cy/CU (measured R3-R5 plateau);
// route the 33.5M random table reads through LDS instead:
//   - block = 1024 threads, owns 512 contiguous rays (65536 samples, 64/thread)
//   - per-sample 20-bit leaf packed as 16-bit offset + 4-bit segment nibble (regs)
//   - 16 segments x 128KiB fp16 staged L2->LDS; exec-masked ds_read for matches
//   - ops written back to the same 128KiB LDS; R5-style (P,S) scan runs in-place

#define NRAYS 262144
#define LEN   128
#define NLEAF 1048576
#define MAXD  1e10f
#define EPSW  1e-10f

#define NSEG     16
#define SEG_ENT  65536            // fp16 entries per segment = 128 KiB
#define THREADS  1024
#define RAYS_PB  512
#define SAMP_PB  65536            // RAYS_PB * LEN
#define NBLK     (NRAYS / RAYS_PB)

typedef float        v4f __attribute__((ext_vector_type(4)));
typedef int          v4i __attribute__((ext_vector_type(4)));
typedef unsigned int v4u __attribute__((ext_vector_type(4)));
typedef unsigned int v2u __attribute__((ext_vector_type(2)));

__device__ __forceinline__ float fast_sigmoid(float x) {
    return __builtin_amdgcn_rcpf(1.0f + __expf(-x));
}
// 1 - exp(-x), x >= 0. Poly for small x (rel err < 2e-7 for x < 0.1).
__device__ __forceinline__ float omexp(float x) {
    float p = x * (1.0f + x * (-0.5f + x * (0.16666667f - 0.041666668f * x)));
    return (x < 0.1f) ? p : (1.0f - __expf(-x));
}
__device__ __forceinline__ float h2f_bits(unsigned u) {
    __half h;
    *(unsigned short*)&h = (unsigned short)u;
    return __half2float(h);
}

__global__ __launch_bounds__(256) void sig_kernel(const float* __restrict__ logits,
                                                  __half* __restrict__ tab) {
    int i = blockIdx.x * 256 + threadIdx.x;   // grid = NLEAF/256
    tab[i] = __float2half(fast_sigmoid(logits[i]));
}

__global__ __launch_bounds__(THREADS) void vc_fused(
    const float*          __restrict__ t_stops,   // [R, L]
    const int*            __restrict__ leaves,    // [R, L]
    const unsigned short* __restrict__ tab,       // fp16 sigmoid table bits [1M]
    float*                __restrict__ out)       // [R]
{
    __shared__ unsigned short lds16[SEG_ENT];     // 128 KiB

    const int tid = threadIdx.x;
    const long long s0 = (long long)blockIdx.x * SAMP_PB;

    // ---- load this thread's 64 samples' leaves; pack offsets + segment nibbles
    unsigned offs[32];   // 2 x u16 offsets per dword
    unsigned segn[8];    // 8 x u4 segment ids per dword
    unsigned us[32];     // 2 x fp16 op results per dword
    #pragma unroll
    for (int k = 0; k < 16; ++k) {
        v4i lv = __builtin_nontemporal_load((const v4i*)(leaves + s0 + k*4096 + tid*4));
        unsigned l0 = (unsigned)lv.x, l1 = (unsigned)lv.y,
                 l2 = (unsigned)lv.z, l3 = (unsigned)lv.w;
        offs[2*k]   = (l0 & 0xFFFFu) | (l1 << 16);
        offs[2*k+1] = (l2 & 0xFFFFu) | (l3 << 16);
        unsigned nib = (l0 >> 16) | ((l1 >> 16) << 4) |
                       ((l2 >> 16) << 8) | ((l3 >> 16) << 12);
        if ((k & 1) == 0) segn[k >> 1] = nib;
        else              segn[k >> 1] |= nib << 16;
    }
    #pragma unroll
    for (int d = 0; d < 32; ++d) us[d] = 0u;

    // ---- segment sweep: stage 128KiB of table, fill matching samples' ops
    for (int seg = 0; seg < NSEG; ++seg) {
        __syncthreads();
        #pragma unroll
        for (int it = 0; it < 8; ++it) {
            v4u d = *(const v4u*)(tab + (size_t)seg*SEG_ENT + it*8192 + tid*8);
            *(v4u*)(lds16 + it*8192 + tid*8) = d;
        }
        __syncthreads();
        #pragma unroll
        for (int g = 0; g < 8; ++g) {
            unsigned sd = segn[g];
            unsigned v[8];
            bool     m[8];
            #pragma unroll
            for (int e = 0; e < 8; ++e) {
                int j = g*8 + e;
                m[e] = ((sd >> (4*e)) & 15u) == (unsigned)seg;
                unsigned off = (offs[j>>1] >> ((j&1)*16)) & 0xFFFFu;
                v[e] = 0u;
                if (m[e]) v[e] = (unsigned)lds16[off];
            }
            #pragma unroll
            for (int e = 0; e < 8; ++e) {
                int j = g*8 + e;
                int d = j >> 1;
                unsigned merged = (j & 1) ? ((us[d] & 0x0000FFFFu) | (v[e] << 16))
                                          : ((us[d] & 0xFFFF0000u) | v[e]);
                us[d] = m[e] ? merged : us[d];
            }
        }
    }

    // ---- write ops to LDS (65536 x fp16 = exact 128KiB reuse)
    __syncthreads();
    #pragma unroll
    for (int k = 0; k < 16; ++k) {
        v2u w;  w.x = us[2*k];  w.y = us[2*k+1];
        *(v2u*)(lds16 + k*4096 + tid*4) = w;     // sample_local = k*4096 + tid*4
    }
    __syncthreads();

    // ---- in-block scan: 8 lanes/ray, 16 samples/lane, 4 sweeps x 128 rays
    const int lane  = tid & 63;
    const int wid   = tid >> 6;
    const int sub   = lane & 7;
    const int gbase = lane & 56;

    for (int sw = 0; sw < 4; ++sw) {
        const int rloc = sw*128 + wid*8 + (lane >> 3);
        const long long rg = (long long)blockIdx.x * RAYS_PB + rloc;
        const long long tb = rg * LEN + sub*4;
        const int       ob = rloc * LEN + sub*4;

        v4f tt[4];
        v2u ow[4];
        #pragma unroll
        for (int c = 0; c < 4; ++c)
            tt[c] = __builtin_nontemporal_load((const v4f*)(t_stops + tb + c*32));
        #pragma unroll
        for (int c = 0; c < 4; ++c)
            ow[c] = *(const v2u*)(lds16 + ob + c*32);

        float P[4], S[4];
        #pragma unroll
        for (int c = 0; c < 4; ++c) {
            float nxt_dn = __shfl_down(tt[c].x, 1);
            float nxt_c1 = (c < 3) ? __shfl(tt[(c+1)&3].x, gbase) : MAXD;
            float nxt = (sub == 7) ? nxt_c1 : nxt_dn;

            float d0 = tt[c].y - tt[c].x;
            float d1 = tt[c].z - tt[c].y;
            float d2 = tt[c].w - tt[c].z;
            float d3 = nxt - tt[c].w;

            float a0 = omexp(h2f_bits(ow[c].x & 0xFFFFu) * d0);
            float a1 = omexp(h2f_bits(ow[c].x >> 16)     * d1);
            float a2 = omexp(h2f_bits(ow[c].y & 0xFFFFu) * d2);
            float a3 = omexp(h2f_bits(ow[c].y >> 16)     * d3);

            float r0 = fminf(1.0f, 1.0f - a0 + EPSW);
            float r1 = fminf(1.0f, 1.0f - a1 + EPSW);
            float r2 = fminf(1.0f, 1.0f - a2 + EPSW);
            float r3 = fminf(1.0f, 1.0f - a3 + EPSW);
            if (c == 0 && sub == 0) r0 = 1.0f;   // ray's trans[0] excluded everywhere

            float cc = r0;        float ss = a0 * cc;
            cc *= r1;             ss = fmaf(a1, cc, ss);
            cc *= r2;             ss = fmaf(a2, cc, ss);
            cc *= r3;             ss = fmaf(a3, cc, ss);
            P[c] = cc;  S[c] = ss;
        }

        // ordered butterfly over the 8-lane ray group
        #pragma unroll
        for (int o = 1; o < 8; o <<= 1) {
            #pragma unroll
            for (int c = 0; c < 4; ++c) {
                float Pp = __shfl_xor(P[c], o);
                float Sp = __shfl_xor(S[c], o);
                S[c] = (lane & o) ? fmaf(Pp, S[c], Sp) : fmaf(P[c], Sp, S[c]);
                P[c] *= Pp;
            }
        }
        float Sr = fmaf(P[2], S[3], S[2]);
        Sr = fmaf(P[1], Sr, S[1]);
        Sr = fmaf(P[0], Sr, S[0]);

        if (sub == 0)
            out[rg] = Sr;
    }
}

// ---- fallback (ws too small): R5-style direct-gather kernel -----------------
__global__ __launch_bounds__(256) void vc_direct(
    const float* __restrict__ t_stops,
    const int*   __restrict__ leaves,
    const float* __restrict__ logits,
    float*       __restrict__ out)
{
    const int lane = threadIdx.x & 63;
    const int wid  = blockIdx.x * 4 + (threadIdx.x >> 6);
    const int ray  = wid * 8 + (lane >> 3);
    const int sub  = lane & 7;
    const int gbase = lane & 56;
    const long long rb = (long long)ray * LEN + sub * 4;

    v4i lv[4]; v4f tt[4];
    #pragma unroll
    for (int c = 0; c < 4; ++c)
        lv[c] = __builtin_nontemporal_load((const v4i*)(leaves + rb + c * 32));
    #pragma unroll
    for (int c = 0; c < 4; ++c)
        tt[c] = __builtin_nontemporal_load((const v4f*)(t_stops + rb + c * 32));

    float op[4][4];
    #pragma unroll
    for (int c = 0; c < 4; ++c) {
        op[c][0] = fast_sigmoid(logits[lv[c].x]);
        op[c][1] = fast_sigmoid(logits[lv[c].y]);
        op[c][2] = fast_sigmoid(logits[lv[c].z]);
        op[c][3] = fast_sigmoid(logits[lv[c].w]);
    }

    float P[4], S[4];
    #pragma unroll
    for (int c = 0; c < 4; ++c) {
        float nxt_dn = __shfl_down(tt[c].x, 1);
        float nxt_c1 = (c < 3) ? __shfl(tt[(c + 1) & 3].x, gbase) : MAXD;
        float nxt = (sub == 7) ? nxt_c1 : nxt_dn;
        float d0 = tt[c].y - tt[c].x;
        float d1 = tt[c].z - tt[c].y;
        float d2 = tt[c].w - tt[c].z;
        float d3 = nxt - tt[c].w;
        float a0 = omexp(op[c][0] * d0);
        float a1 = omexp(op[c][1] * d1);
        float a2 = omexp(op[c][2] * d2);
        float a3 = omexp(op[c][3] * d3);
        float r0 = fminf(1.0f, 1.0f - a0 + EPSW);
        float r1 = fminf(1.0f, 1.0f - a1 + EPSW);
        float r2 = fminf(1.0f, 1.0f - a2 + EPSW);
        float r3 = fminf(1.0f, 1.0f - a3 + EPSW);
        if (c == 0 && sub == 0) r0 = 1.0f;
        float cc = r0;        float ss = a0 * cc;
        cc *= r1;             ss = fmaf(a1, cc, ss);
        cc *= r2;             ss = fmaf(a2, cc, ss);
        cc *= r3;             ss = fmaf(a3, cc, ss);
        P[c] = cc;  S[c] = ss;
    }
    #pragma unroll
    for (int o = 1; o < 8; o <<= 1) {
        #pragma unroll
        for (int c = 0; c < 4; ++c) {
            float Pp = __shfl_xor(P[c], o);
            float Sp = __shfl_xor(S[c], o);
            S[c] = (lane & o) ? fmaf(Pp, S[c], Sp) : fmaf(P[c], Sp, S[c]);
            P[c] *= Pp;
        }
    }
    float Sr = fmaf(P[2], S[3], S[2]);
    Sr = fmaf(P[1], Sr, S[1]);
    Sr = fmaf(P[0], Sr, S[0]);
    if (sub == 0)
        out[ray] = Sr;
}

extern "C" void kernel_launch(void* const* d_in, const int* in_sizes, int n_in,
                              void* d_out, int out_size, void* d_ws, size_t ws_size,
                              hipStream_t stream) {
    const float* t_stops = (const float*)d_in[0];
    const int*   leaves  = (const int*)d_in[1];
    const float* logits  = (const float*)d_in[2];
    float*       out     = (float*)d_out;

    if (ws_size >= NLEAF * sizeof(__half)) {
        sig_kernel<<<NLEAF / 256, 256, 0, stream>>>(logits, (__half*)d_ws);
        vc_fused<<<NBLK, THREADS, 0, stream>>>(t_stops, leaves,
                                               (const unsigned short*)d_ws, out);
    } else {
        vc_direct<<<NRAYS / 32, 256, 0, stream>>>(t_stops, leaves, logits, out);
    }
}

// Round 7
// 402.082 us; speedup vs baseline: 4.3347x; 4.3347x over previous
//
#include <hip/hip_runtime.h>
#include <hip/hip_fp16.h>
#include <math.h>

// VolumeCarver R7: split gather/scan.
// R3-R5 measured a hard ~0.49 lane-gathers/cy/CU plateau in the fused kernel.
// This round isolates the divergent gather into a dedicated kernel (nothing in
// the wave but 16 independent ushort gathers + packed coalesced stores) to
// test whether the cap is structural (wave interleave) or a machine limit.
//   K1 sig:    logits -> fp16 sigmoid table (2 MB, L2-resident)
//   K2 gather: leaves -> ops[i] = tab[leaves[i]]  (fp16, coalesced 32B/thread out)
//   K3 scan:   t_stops + ops (both streamed) -> R5's (P,S) monoid scan
// Fallback (small ws): R5 fused direct-gather kernel.

#define NRAYS 262144
#define LEN   128
#define NSAMP (NRAYS * LEN)
#define NLEAF 1048576
#define MAXD  1e10f
#define EPSW  1e-10f

typedef float        v4f __attribute__((ext_vector_type(4)));
typedef int          v4i __attribute__((ext_vector_type(4)));
typedef unsigned int v4u __attribute__((ext_vector_type(4)));
typedef unsigned int v2u __attribute__((ext_vector_type(2)));

__device__ __forceinline__ float fast_sigmoid(float x) {
    return __builtin_amdgcn_rcpf(1.0f + __expf(-x));
}
// 1 - exp(-x), x >= 0. Poly for small x (rel err < 2e-7 for x < 0.1).
__device__ __forceinline__ float omexp(float x) {
    float p = x * (1.0f + x * (-0.5f + x * (0.16666667f - 0.041666668f * x)));
    return (x < 0.1f) ? p : (1.0f - __expf(-x));
}
__device__ __forceinline__ float h2f_bits(unsigned u) {
    __half h;
    *(unsigned short*)&h = (unsigned short)u;
    return __half2float(h);
}

__global__ __launch_bounds__(256) void sig_kernel(const float* __restrict__ logits,
                                                  __half* __restrict__ tab) {
    int i = blockIdx.x * 256 + threadIdx.x;   // grid = NLEAF/256
    tab[i] = __float2half(fast_sigmoid(logits[i]));
}

// K2: pure gather. 16 samples/thread; minimal VALU; max outstanding gathers.
__global__ __launch_bounds__(256) void gather_kernel(
    const int*            __restrict__ leaves,  // [NSAMP]
    const unsigned short* __restrict__ tab,     // fp16 table bits [NLEAF]
    unsigned short*       __restrict__ ops)     // [NSAMP] fp16 bits out
{
    const long long base =
        ((long long)blockIdx.x * 256 + threadIdx.x) * 16;   // grid covers NSAMP/16

    v4i l0 = __builtin_nontemporal_load((const v4i*)(leaves + base));
    v4i l1 = __builtin_nontemporal_load((const v4i*)(leaves + base + 4));
    v4i l2 = __builtin_nontemporal_load((const v4i*)(leaves + base + 8));
    v4i l3 = __builtin_nontemporal_load((const v4i*)(leaves + base + 12));

    // 16 independent divergent gathers, all issued before any use.
    unsigned u0  = tab[l0.x], u1  = tab[l0.y], u2  = tab[l0.z], u3  = tab[l0.w];
    unsigned u4  = tab[l1.x], u5  = tab[l1.y], u6  = tab[l1.z], u7  = tab[l1.w];
    unsigned u8  = tab[l2.x], u9  = tab[l2.y], u10 = tab[l2.z], u11 = tab[l2.w];
    unsigned u12 = tab[l3.x], u13 = tab[l3.y], u14 = tab[l3.z], u15 = tab[l3.w];

    v4u w0, w1;
    w0.x = u0  | (u1  << 16);  w0.y = u2  | (u3  << 16);
    w0.z = u4  | (u5  << 16);  w0.w = u6  | (u7  << 16);
    w1.x = u8  | (u9  << 16);  w1.y = u10 | (u11 << 16);
    w1.z = u12 | (u13 << 16);  w1.w = u14 | (u15 << 16);

    __builtin_nontemporal_store(w0, (v4u*)(ops + base));
    __builtin_nontemporal_store(w1, (v4u*)(ops + base + 8));
}

// K3: pure-streaming scan (R5 structure; ops from scratch instead of gathers).
__global__ __launch_bounds__(256) void scan_kernel(
    const float*          __restrict__ t_stops,  // [R, L]
    const unsigned short* __restrict__ ops,      // [R, L] fp16 bits
    float*                __restrict__ out)      // [R]
{
    const int lane = threadIdx.x & 63;
    const int wid  = blockIdx.x * 4 + (threadIdx.x >> 6);
    const int ray  = wid * 8 + (lane >> 3);          // 8 rays per wave
    const int sub  = lane & 7;                       // 8 lanes per ray
    const int gbase = lane & 56;
    const long long rb = (long long)ray * LEN + sub * 4;

    v4f tt[4];
    v2u ow[4];
    #pragma unroll
    for (int c = 0; c < 4; ++c)
        tt[c] = __builtin_nontemporal_load((const v4f*)(t_stops + rb + c * 32));
    #pragma unroll
    for (int c = 0; c < 4; ++c)
        ow[c] = __builtin_nontemporal_load((const v2u*)(ops + rb + c * 32));

    float P[4], S[4];
    #pragma unroll
    for (int c = 0; c < 4; ++c) {
        float nxt_dn = __shfl_down(tt[c].x, 1);
        float nxt_c1 = (c < 3) ? __shfl(tt[(c + 1) & 3].x, gbase) : MAXD;
        float nxt = (sub == 7) ? nxt_c1 : nxt_dn;

        float d0 = tt[c].y - tt[c].x;
        float d1 = tt[c].z - tt[c].y;
        float d2 = tt[c].w - tt[c].z;
        float d3 = nxt - tt[c].w;

        float a0 = omexp(h2f_bits(ow[c].x & 0xFFFFu) * d0);
        float a1 = omexp(h2f_bits(ow[c].x >> 16)     * d1);
        float a2 = omexp(h2f_bits(ow[c].y & 0xFFFFu) * d2);
        float a3 = omexp(h2f_bits(ow[c].y >> 16)     * d3);

        float r0 = fminf(1.0f, 1.0f - a0 + EPSW);
        float r1 = fminf(1.0f, 1.0f - a1 + EPSW);
        float r2 = fminf(1.0f, 1.0f - a2 + EPSW);
        float r3 = fminf(1.0f, 1.0f - a3 + EPSW);
        if (c == 0 && sub == 0) r0 = 1.0f;   // ray's trans[0] excluded everywhere

        float cc = r0;        float ss = a0 * cc;
        cc *= r1;             ss = fmaf(a1, cc, ss);
        cc *= r2;             ss = fmaf(a2, cc, ss);
        cc *= r3;             ss = fmaf(a3, cc, ss);
        P[c] = cc;  S[c] = ss;
    }

    #pragma unroll
    for (int o = 1; o < 8; o <<= 1) {
        #pragma unroll
        for (int c = 0; c < 4; ++c) {
            float Pp = __shfl_xor(P[c], o);
            float Sp = __shfl_xor(S[c], o);
            S[c] = (lane & o) ? fmaf(Pp, S[c], Sp) : fmaf(P[c], Sp, S[c]);
            P[c] *= Pp;
        }
    }
    float Sr = fmaf(P[2], S[3], S[2]);
    Sr = fmaf(P[1], Sr, S[1]);
    Sr = fmaf(P[0], Sr, S[0]);
    if (sub == 0)
        out[ray] = Sr;
}

// ---- fallback (ws too small): R5 fused direct-gather kernel ----------------
__global__ __launch_bounds__(256) void vc_direct(
    const float* __restrict__ t_stops,
    const int*   __restrict__ leaves,
    const float* __restrict__ logits,
    float*       __restrict__ out)
{
    const int lane = threadIdx.x & 63;
    const int wid  = blockIdx.x * 4 + (threadIdx.x >> 6);
    const int ray  = wid * 8 + (lane >> 3);
    const int sub  = lane & 7;
    const int gbase = lane & 56;
    const long long rb = (long long)ray * LEN + sub * 4;

    v4i lv[4]; v4f tt[4];
    #pragma unroll
    for (int c = 0; c < 4; ++c)
        lv[c] = __builtin_nontemporal_load((const v4i*)(leaves + rb + c * 32));
    #pragma unroll
    for (int c = 0; c < 4; ++c)
        tt[c] = __builtin_nontemporal_load((const v4f*)(t_stops + rb + c * 32));

    float op[4][4];
    #pragma unroll
    for (int c = 0; c < 4; ++c) {
        op[c][0] = fast_sigmoid(logits[lv[c].x]);
        op[c][1] = fast_sigmoid(logits[lv[c].y]);
        op[c][2] = fast_sigmoid(logits[lv[c].z]);
        op[c][3] = fast_sigmoid(logits[lv[c].w]);
    }

    float P[4], S[4];
    #pragma unroll
    for (int c = 0; c < 4; ++c) {
        float nxt_dn = __shfl_down(tt[c].x, 1);
        float nxt_c1 = (c < 3) ? __shfl(tt[(c + 1) & 3].x, gbase) : MAXD;
        float nxt = (sub == 7) ? nxt_c1 : nxt_dn;
        float d0 = tt[c].y - tt[c].x;
        float d1 = tt[c].z - tt[c].y;
        float d2 = tt[c].w - tt[c].z;
        float d3 = nxt - tt[c].w;
        float a0 = omexp(op[c][0] * d0);
        float a1 = omexp(op[c][1] * d1);
        float a2 = omexp(op[c][2] * d2);
        float a3 = omexp(op[c][3] * d3);
        float r0 = fminf(1.0f, 1.0f - a0 + EPSW);
        float r1 = fminf(1.0f, 1.0f - a1 + EPSW);
        float r2 = fminf(1.0f, 1.0f - a2 + EPSW);
        float r3 = fminf(1.0f, 1.0f - a3 + EPSW);
        if (c == 0 && sub == 0) r0 = 1.0f;
        float cc = r0;        float ss = a0 * cc;
        cc *= r1;             ss = fmaf(a1, cc, ss);
        cc *= r2;             ss = fmaf(a2, cc, ss);
        cc *= r3;             ss = fmaf(a3, cc, ss);
        P[c] = cc;  S[c] = ss;
    }
    #pragma unroll
    for (int o = 1; o < 8; o <<= 1) {
        #pragma unroll
        for (int c = 0; c < 4; ++c) {
            float Pp = __shfl_xor(P[c], o);
            float Sp = __shfl_xor(S[c], o);
            S[c] = (lane & o) ? fmaf(Pp, S[c], Sp) : fmaf(P[c], Sp, S[c]);
            P[c] *= Pp;
        }
    }
    float Sr = fmaf(P[2], S[3], S[2]);
    Sr = fmaf(P[1], Sr, S[1]);
    Sr = fmaf(P[0], Sr, S[0]);
    if (sub == 0)
        out[ray] = Sr;
}

extern "C" void kernel_launch(void* const* d_in, const int* in_sizes, int n_in,
                              void* d_out, int out_size, void* d_ws, size_t ws_size,
                              hipStream_t stream) {
    const float* t_stops = (const float*)d_in[0];
    const int*   leaves  = (const int*)d_in[1];
    const float* logits  = (const float*)d_in[2];
    float*       out     = (float*)d_out;

    const size_t need = (size_t)NLEAF * 2 + (size_t)NSAMP * 2;  // table + ops
    if (ws_size >= need) {
        __half*         tab = (__half*)d_ws;
        unsigned short* ops = (unsigned short*)d_ws + NLEAF;
        sig_kernel<<<NLEAF / 256, 256, 0, stream>>>(logits, tab);
        gather_kernel<<<NSAMP / 16 / 256, 256, 0, stream>>>(
            leaves, (const unsigned short*)tab, ops);
        scan_kernel<<<NRAYS / 32, 256, 0, stream>>>(t_stops, ops, out);
    } else {
        vc_direct<<<NRAYS / 32, 256, 0, stream>>>(t_stops, leaves, logits, out);
    }
}

// Round 8
// 367.053 us; speedup vs baseline: 4.7484x; 1.0954x over previous
//
#include <hip/hip_runtime.h>
#include <hip/hip_fp16.h>
#include <math.h>

// VolumeCarver R8 = revert to R5 (best config; kernel time == pure-gather floor).
//
// Measured across R3-R7: 33.5M random 2B gathers from the L2-resident fp16
// sigmoid table pin at ~0.33 lane-gathers/cy/CU no matter the structure
// (fused or isolated, 8 or 16 in flight, L1-bypassed or not). The fused
// kernel's duration (165us) equals the isolated pure-gather kernel (166us),
// i.e. all streaming + VALU + scan work is fully hidden behind the gather cap.
// This kernel is at that machine roofline.
//
//   K1 sig:  logits -> fp16 sigmoid table (2 MB, stays L2-resident)
//   K2 fused: per-wave 8 rays x 8 lanes, 16 samples/lane; dword-aligned table
//            gathers; (P,S) monoid butterfly scan; one store per ray.

#define NRAYS 262144
#define LEN   128
#define NLEAF 1048576
#define MAXD  1e10f
#define EPSW  1e-10f

typedef float v4f __attribute__((ext_vector_type(4)));
typedef int   v4i __attribute__((ext_vector_type(4)));

__device__ __forceinline__ float fast_sigmoid(float x) {
    return __builtin_amdgcn_rcpf(1.0f + __expf(-x));
}

// 1 - exp(-x), x >= 0. Poly for small x (rel err < 2e-7 for x < 0.1).
__device__ __forceinline__ float omexp(float x) {
    float p = x * (1.0f + x * (-0.5f + x * (0.16666667f - 0.041666668f * x)));
    return (x < 0.1f) ? p : (1.0f - __expf(-x));
}

// Dword-aligned gather of fp16 entry idx from table (2B entries packed in dwords).
__device__ __forceinline__ float tab_gather32(const unsigned int* tb32, int idx) {
    unsigned int v = tb32[idx >> 1];
    unsigned short u = (unsigned short)(v >> ((idx & 1) * 16));
    __half h;
    *(unsigned short*)&h = u;
    return __half2float(h);
}

__global__ __launch_bounds__(256) void sig_kernel(const float* __restrict__ logits,
                                                  __half* __restrict__ tab) {
    int i = blockIdx.x * 256 + threadIdx.x;   // grid = NLEAF/256
    tab[i] = __float2half(fast_sigmoid(logits[i]));
}

template <bool TAB>
__global__ __launch_bounds__(256) void vc_kernel(
    const float* __restrict__ t_stops,   // [R, L]
    const int*   __restrict__ leaves,    // [R, L]
    const void*  __restrict__ table,     // fp16 sigmoid table (TAB) or raw f32 logits
    float*       __restrict__ out)       // [R]
{
    const int lane = threadIdx.x & 63;
    const int wid  = blockIdx.x * 4 + (threadIdx.x >> 6);
    const int ray  = wid * 8 + (lane >> 3);          // 8 rays per wave
    const int sub  = lane & 7;                       // 8 lanes per ray
    const int gbase = lane & 56;                     // first lane of this ray group

    // chunk c covers elements [c*32 + sub*4 .. +3] of the ray (c = 0..3)
    const long long rb = (long long)ray * LEN + sub * 4;

    v4i lv[4];
    v4f tt[4];
    #pragma unroll
    for (int c = 0; c < 4; ++c)
        lv[c] = __builtin_nontemporal_load((const v4i*)(leaves + rb + c * 32));
    #pragma unroll
    for (int c = 0; c < 4; ++c)
        tt[c] = __builtin_nontemporal_load((const v4f*)(t_stops + rb + c * 32));

    // 16 independent gathers issued back-to-back.
    float op[4][4];
    if (TAB) {
        const unsigned int* tb32 = (const unsigned int*)table;
        #pragma unroll
        for (int c = 0; c < 4; ++c) {
            op[c][0] = tab_gather32(tb32, lv[c].x);
            op[c][1] = tab_gather32(tb32, lv[c].y);
            op[c][2] = tab_gather32(tb32, lv[c].z);
            op[c][3] = tab_gather32(tb32, lv[c].w);
        }
    } else {
        const float* lg = (const float*)table;
        #pragma unroll
        for (int c = 0; c < 4; ++c) {
            op[c][0] = fast_sigmoid(lg[lv[c].x]);
            op[c][1] = fast_sigmoid(lg[lv[c].y]);
            op[c][2] = fast_sigmoid(lg[lv[c].z]);
            op[c][3] = fast_sigmoid(lg[lv[c].w]);
        }
    }

    // Per-chunk local (P,S) over the lane's 4 consecutive elements.
    float P[4], S[4];
    #pragma unroll
    for (int c = 0; c < 4; ++c) {
        // value of the element AFTER this lane's last one in chunk c:
        //   sub<7 : next lane's tt[c].x
        //   sub==7: chunk c+1's tt.x at group's lane 0 (or MAXD at ray end)
        float nxt_dn = __shfl_down(tt[c].x, 1);
        float nxt_c1 = (c < 3) ? __shfl(tt[(c + 1) & 3].x, gbase) : MAXD;
        float nxt = (sub == 7) ? nxt_c1 : nxt_dn;

        float d0 = tt[c].y - tt[c].x;
        float d1 = tt[c].z - tt[c].y;
        float d2 = tt[c].w - tt[c].z;
        float d3 = nxt - tt[c].w;

        float a0 = omexp(op[c][0] * d0);
        float a1 = omexp(op[c][1] * d1);
        float a2 = omexp(op[c][2] * d2);
        float a3 = omexp(op[c][3] * d3);

        float r0 = fminf(1.0f, 1.0f - a0 + EPSW);
        float r1 = fminf(1.0f, 1.0f - a1 + EPSW);
        float r2 = fminf(1.0f, 1.0f - a2 + EPSW);
        float r3 = fminf(1.0f, 1.0f - a3 + EPSW);
        if (c == 0 && sub == 0) r0 = 1.0f;   // ray's trans[0] excluded everywhere

        float cc = r0;        float ss = a0 * cc;
        cc *= r1;             ss = fmaf(a1, cc, ss);
        cc *= r2;             ss = fmaf(a2, cc, ss);
        cc *= r3;             ss = fmaf(a3, cc, ss);
        P[c] = cc;  S[c] = ss;
    }

    // Ordered butterfly over the 8-lane ray group, all 4 chunks concurrently.
    #pragma unroll
    for (int o = 1; o < 8; o <<= 1) {
        #pragma unroll
        for (int c = 0; c < 4; ++c) {
            float Pp = __shfl_xor(P[c], o);
            float Sp = __shfl_xor(S[c], o);
            S[c] = (lane & o) ? fmaf(Pp, S[c], Sp) : fmaf(P[c], Sp, S[c]);
            P[c] *= Pp;
        }
    }

    // Chain the 4 chunk segments in order.
    float Sr = fmaf(P[2], S[3], S[2]);
    Sr = fmaf(P[1], Sr, S[1]);
    Sr = fmaf(P[0], Sr, S[0]);

    if (sub == 0)
        out[ray] = Sr;
}

extern "C" void kernel_launch(void* const* d_in, const int* in_sizes, int n_in,
                              void* d_out, int out_size, void* d_ws, size_t ws_size,
                              hipStream_t stream) {
    const float* t_stops = (const float*)d_in[0];
    const int*   leaves  = (const int*)d_in[1];
    const float* logits  = (const float*)d_in[2];
    float*       out     = (float*)d_out;

    if (ws_size >= NLEAF * sizeof(__half)) {
        sig_kernel<<<NLEAF / 256, 256, 0, stream>>>(logits, (__half*)d_ws);
        // 32 rays per 256-thread block (8 rays per wave)
        vc_kernel<true><<<NRAYS / 32, 256, 0, stream>>>(t_stops, leaves, d_ws, out);
    } else {
        vc_kernel<false><<<NRAYS / 32, 256, 0, stream>>>(t_stops, leaves, logits, out);
    }
}